// Round 14
// baseline (222.198 us; speedup 1.0000x reference)
//
#include <hip/hip_runtime.h>
#include <cmath>

#define FEAT_DIM 1024
#define MM 32
#define KK 256
#define DD 32
#define BB 8192

constexpr float BN_EPS = 1e-5f;

typedef float f32x4 __attribute__((ext_vector_type(4)));

__device__ __forceinline__ float wave_fsum(float v) {
    #pragma unroll
    for (int s = 32; s >= 1; s >>= 1) v += __shfl_xor(v, s);
    return v;
}

// ---- DPP-based full-wave reductions: VALU-rate, result broadcast via SGPR ----
template <int CTRL, int RM = 0xf>
__device__ __forceinline__ float dppf(float v) {
    int r = __builtin_amdgcn_update_dpp(__builtin_bit_cast(int, v),
                                        __builtin_bit_cast(int, v),
                                        CTRL, RM, 0xf, false);
    return __builtin_bit_cast(float, r);
}
__device__ __forceinline__ float wave_dpp_max(float v) {
    v = fmaxf(v, dppf<0xB1>(v));
    v = fmaxf(v, dppf<0x4E>(v));
    v = fmaxf(v, dppf<0x141>(v));
    v = fmaxf(v, dppf<0x140>(v));
    v = fmaxf(v, dppf<0x142, 0xa>(v));
    v = fmaxf(v, dppf<0x143, 0xc>(v));
    return __builtin_bit_cast(float, __builtin_amdgcn_readlane(__builtin_bit_cast(int, v), 63));
}
__device__ __forceinline__ float wave_dpp_sum(float v) {
    v += dppf<0xB1>(v);
    v += dppf<0x4E>(v);
    v += dppf<0x141>(v);
    v += dppf<0x140>(v);
    v += dppf<0x142, 0xa>(v);
    v += dppf<0x143, 0xc>(v);
    return __builtin_bit_cast(float, __builtin_amdgcn_readlane(__builtin_bit_cast(int, v), 63));
}

// ---------- P0: per-m codebook sums S_m and Gram G_m = C^T C; zero stats ----------
__global__ void k_gram(const float* __restrict__ Ck, float* __restrict__ G,
                       float* __restrict__ S, double* __restrict__ stats) {
    __shared__ float CT[DD][KK + 4];
    const int m = blockIdx.x, part = blockIdx.y;
    const int t = threadIdx.x, wid = t >> 6, lane = t & 63;
    if (m == 0 && part == 0 && t < 2 * MM) stats[t] = 0.0;
    const float4* cp = (const float4*)(Ck + ((size_t)m * KK + t) * DD);
    #pragma unroll
    for (int i = 0; i < 8; ++i) {
        float4 v = cp[i];
        CT[4*i+0][t] = v.x; CT[4*i+1][t] = v.y;
        CT[4*i+2][t] = v.z; CT[4*i+3][t] = v.w;
    }
    __syncthreads();
    #pragma unroll 1
    for (int ei = 0; ei < 32; ++ei) {
        const int e = part * 128 + wid * 32 + ei;
        const int i = e >> 5, j = e & 31;
        float acc = 0.f;
        #pragma unroll
        for (int c4 = 0; c4 < 4; ++c4)
            acc = fmaf(CT[i][lane + 64*c4], CT[j][lane + 64*c4], acc);
        acc = wave_fsum(acc);
        if (lane == 0) G[((size_t)m * DD + i) * DD + j] = acc;
    }
    if (part == 0 && wid == 0) {
        #pragma unroll 1
        for (int d = 0; d < DD; ++d) {
            float a = 0.f;
            #pragma unroll
            for (int c4 = 0; c4 < 4; ++c4) a += CT[d][lane + 64*c4];
            a = wave_fsum(a);
            if (lane == 0) S[m * DD + d] = a;
        }
    }
}

// ---------- P1: FUSED normalize + stats (one x pass, thread-per-(b,m)) ----------
__global__ void k_ns(const float* __restrict__ x, float* __restrict__ xn,
                     const float* __restrict__ G, const float* __restrict__ S,
                     double* __restrict__ stats) {
    const int m = blockIdx.x;
    const int b = blockIdx.y * 256 + threadIdx.x;
    float xv[DD];
    {
        const float4* xp = (const float4*)(x + (size_t)b * FEAT_DIM + m * DD);
        #pragma unroll
        for (int i = 0; i < 8; ++i) {
            float4 v = xp[i];
            xv[4*i+0]=v.x; xv[4*i+1]=v.y; xv[4*i+2]=v.z; xv[4*i+3]=v.w;
        }
    }
    float ss = 0.f;
    #pragma unroll
    for (int i = 0; i < DD; ++i) ss = fmaf(xv[i], xv[i], ss);
    const float rn = 1.0f / fmaxf(sqrtf(ss), 1e-12f);
    {
        float4* op = (float4*)(xn + (size_t)b * FEAT_DIM + m * DD);
        #pragma unroll
        for (int i = 0; i < 8; ++i) {
            float4 o = {xv[4*i+0]*rn, xv[4*i+1]*rn, xv[4*i+2]*rn, xv[4*i+3]*rn};
            op[i] = o;
        }
    }
    // quadratic form on RAW x, scaled after: sum = rn*(x.S), sumsq = rn^2*(x^T G x)
    const float4* Gp = (const float4*)(G + (size_t)m * DD * DD);   // block-uniform
    const float*  Sp = S + m * DD;
    float q = 0.f, s = 0.f;
    #pragma unroll 4
    for (int i = 0; i < DD; ++i) {
        float y = 0.f;
        #pragma unroll
        for (int jv = 0; jv < 8; ++jv) {
            float4 g = Gp[i * 8 + jv];
            y = fmaf(g.x, xv[4*jv+0], y); y = fmaf(g.y, xv[4*jv+1], y);
            y = fmaf(g.z, xv[4*jv+2], y); y = fmaf(g.w, xv[4*jv+3], y);
        }
        q = fmaf(y, xv[i], q);
    }
    #pragma unroll
    for (int i = 0; i < DD; ++i) s = fmaf(Sp[i], xv[i], s);
    q = q * rn * rn;
    s = s * rn;
    q = wave_fsum(q); s = wave_fsum(s);
    __shared__ float lq[4], ls[4];
    const int wid = threadIdx.x >> 6, lane = threadIdx.x & 63;
    if (lane == 0) { lq[wid] = q; ls[wid] = s; }
    __syncthreads();
    if (threadIdx.x == 0) {
        atomicAdd(&stats[2*m],   (double)((ls[0]+ls[1])+(ls[2]+ls[3])));
        atomicAdd(&stats[2*m+1], (double)((lq[0]+lq[1])+(lq[2]+lq[3])));
    }
}

// ---------- P2: wave-per-(b,m), R12 hot loop; xhat stored from winner's registers ----
template <int BT>
__global__ __launch_bounds__(256, 2)
void k_main(const float* __restrict__ xn, const float* __restrict__ Ck,
            const double* __restrict__ stats,
            float* __restrict__ xhat, float* __restrict__ hard,
            float* __restrict__ soft, float* __restrict__ part) {
    const int m = blockIdx.x;
    const int wid = threadIdx.x >> 6, lane = threadIdx.x & 63;

    const double Ninv = 1.0 / ((double)BB * (double)KK);
    const double mu  = stats[2*m] * Ninv;
    const double var = stats[2*m+1] * Ninv - mu * mu;
    const float rstd = (float)(1.0 / sqrt(var + (double)BN_EPS));
    // softmax is scale-invariant: p = exp2(d * rstd*log2e); shift cancels
    const float c1 = rstd * 1.4426950408889634f;

    // lane owns codewords k = 4*lane + j, register-resident across the b-loop
    float c[4][DD];
    #pragma unroll
    for (int j = 0; j < 4; ++j) {
        const float4* cp = (const float4*)(Ck + ((size_t)m * KK + 4*lane + j) * DD);
        #pragma unroll
        for (int i = 0; i < 8; ++i) {
            float4 v = cp[i];
            c[j][4*i+0]=v.x; c[j][4*i+1]=v.y; c[j][4*i+2]=v.z; c[j][4*i+3]=v.w;
        }
    }

    const int b_base = blockIdx.y * (4 * BT) + wid;

    auto loadslice = [&](float4 (&q)[8], int b) {
        const int bu = __builtin_amdgcn_readfirstlane(b);
        const float4* xp = (const float4*)(xn + (size_t)bu * FEAT_DIM + m * DD);
        #pragma unroll
        for (int i = 0; i < 8; ++i) q[i] = xp[i];
    };

    auto process = [&](const float4 (&q)[8], int b) {
        float d0=0.f, d1=0.f, d2=0.f, d3=0.f;
        #pragma unroll
        for (int i = 0; i < 8; ++i) {
            const float4 q4 = q[i];
            d0 = fmaf(q4.x, c[0][4*i+0], d0); d0 = fmaf(q4.y, c[0][4*i+1], d0);
            d0 = fmaf(q4.z, c[0][4*i+2], d0); d0 = fmaf(q4.w, c[0][4*i+3], d0);
            d1 = fmaf(q4.x, c[1][4*i+0], d1); d1 = fmaf(q4.y, c[1][4*i+1], d1);
            d1 = fmaf(q4.z, c[1][4*i+2], d1); d1 = fmaf(q4.w, c[1][4*i+3], d1);
            d2 = fmaf(q4.x, c[2][4*i+0], d2); d2 = fmaf(q4.y, c[2][4*i+1], d2);
            d2 = fmaf(q4.z, c[2][4*i+2], d2); d2 = fmaf(q4.w, c[2][4*i+3], d2);
            d3 = fmaf(q4.x, c[3][4*i+0], d3); d3 = fmaf(q4.y, c[3][4*i+1], d3);
            d3 = fmaf(q4.z, c[3][4*i+2], d3); d3 = fmaf(q4.w, c[3][4*i+3], d3);
        }

        // softmax (unshifted, scale-invariant) — chain independent of argmax chain
        const float p0 = exp2f(d0 * c1);
        const float p1 = exp2f(d1 * c1);
        const float p2 = exp2f(d2 * c1);
        const float p3 = exp2f(d3 * c1);

        // argmax: DPP wave-max (SGPR broadcast), ballot + scalar ffs
        const float mx = wave_dpp_max(fmaxf(fmaxf(d0, d1), fmaxf(d2, d3)));
        const unsigned long long m0 = __ballot(d0 == mx);
        const unsigned long long m1 = __ballot(d1 == mx);
        const unsigned long long m2 = __ballot(d2 == mx);
        const unsigned long long m3 = __ballot(d3 == mx);
        const int k0 = m0 ? 4*__builtin_ctzll(m0)+0 : 0x7fffffff;
        const int k1 = m1 ? 4*__builtin_ctzll(m1)+1 : 0x7fffffff;
        const int k2 = m2 ? 4*__builtin_ctzll(m2)+2 : 0x7fffffff;
        const int k3 = m3 ? 4*__builtin_ctzll(m3)+3 : 0x7fffffff;
        const int bi = min(min(k0, k1), min(k2, k3));   // first-index tie-break

        const float tot = wave_dpp_sum((p0 + p1) + (p2 + p3));
        const float inv = __builtin_amdgcn_rcpf(tot);

        f32x4 o = {p0*inv, p1*inv, p2*inv, p3*inv};
        __builtin_nontemporal_store(o, (f32x4*)(soft + ((size_t)b * MM + m) * KK) + lane);
        if (lane == 0) {
            hard[(size_t)b * MM + m] = (float)bi;
            part[(size_t)m * BB + b] = 2.f - 2.f * mx;  // reg identity: 2-2*maxdot
        }
        // xhat from the WINNING lane's registers (no memory gather; j static — no scratch)
        #pragma unroll
        for (int j = 0; j < 4; ++j) {
            if (4 * lane + j == bi) {
                f32x4* xp = (f32x4*)(xhat + (size_t)b * FEAT_DIM + m * DD);
                #pragma unroll
                for (int i = 0; i < 8; ++i) {
                    f32x4 cw = {c[j][4*i+0], c[j][4*i+1], c[j][4*i+2], c[j][4*i+3]};
                    __builtin_nontemporal_store(cw, xp + i);
                }
            }
        }
    };

    // ping-pong double-buffer, no register copies (R6/R12 structure)
    float4 A[8], Bv[8];
    loadslice(A, b_base);
    #pragma unroll 1
    for (int it = 0; it < BT; it += 2) {
        loadslice(Bv, b_base + 4 * (it + 1));           // BT even: it+1 < BT always
        process(A, b_base + 4 * it);
        if (it + 2 < BT) loadslice(A, b_base + 4 * (it + 2));
        process(Bv, b_base + 4 * (it + 1));
    }
}

// ---------- P3: reg[b] = sum_m part[m][b] ----------
__global__ void k_regsum(const float* __restrict__ part, float* __restrict__ reg) {
    const int b = blockIdx.x * 256 + threadIdx.x;
    float a = 0.f;
    #pragma unroll
    for (int mm = 0; mm < MM; ++mm) a += part[(size_t)mm * BB + b];
    reg[b] = a;
}

extern "C" void kernel_launch(void* const* d_in, const int* in_sizes, int n_in,
                              void* d_out, int out_size, void* d_ws, size_t ws_size,
                              hipStream_t stream) {
    const float* x  = (const float*)d_in[0];
    const float* Ck = (const float*)d_in[1];

    float* out   = (float*)d_out;
    float* xhat  = out;                                   // B*FEAT
    float* hard  = xhat  + (size_t)BB * FEAT_DIM;         // B*M
    float* soft  = hard  + (size_t)BB * MM;               // B*M*K
    float* xnorm = soft  + (size_t)BB * MM * KK;          // B*FEAT
    float* reg   = xnorm + (size_t)BB * FEAT_DIM;         // B

    double* stats = (double*)d_ws;                        // M*2 doubles
    float* partb  = (float*)d_ws + 256;                   // M*B floats (1 MB) scratch
    float* Gbuf = soft;                                   // M*D*D floats (scratch, pre-k_main)
    float* Sbuf = soft + (size_t)MM * DD * DD;            // M*D floats

    k_gram<<<dim3(MM, 8), 256, 0, stream>>>(Ck, Gbuf, Sbuf, stats);
    k_ns<<<dim3(MM, BB / 256), 256, 0, stream>>>(x, xnorm, Gbuf, Sbuf, stats);
    constexpr int BT = 32;
    k_main<BT><<<dim3(MM, BB / (4 * BT)), 256, 0, stream>>>(xnorm, Ck, stats, xhat, hard, soft, partb);
    k_regsum<<<BB / 256, 256, 0, stream>>>(partb, reg);
}

// Round 15
// 158.960 us; speedup vs baseline: 1.3978x; 1.3978x over previous
//
#include <hip/hip_runtime.h>
#include <cmath>

#define FEAT_DIM 1024
#define MM 32
#define KK 256
#define DD 32
#define BB 8192

constexpr float BN_EPS = 1e-5f;

typedef float f32x4 __attribute__((ext_vector_type(4)));

__device__ __forceinline__ float wave_fsum(float v) {
    #pragma unroll
    for (int s = 32; s >= 1; s >>= 1) v += __shfl_xor(v, s);
    return v;
}

// ---- DPP-based full-wave reductions: VALU-rate, result broadcast via SGPR ----
template <int CTRL, int RM = 0xf>
__device__ __forceinline__ float dppf(float v) {
    int r = __builtin_amdgcn_update_dpp(__builtin_bit_cast(int, v),
                                        __builtin_bit_cast(int, v),
                                        CTRL, RM, 0xf, false);
    return __builtin_bit_cast(float, r);
}
__device__ __forceinline__ float wave_dpp_max(float v) {
    v = fmaxf(v, dppf<0xB1>(v));
    v = fmaxf(v, dppf<0x4E>(v));
    v = fmaxf(v, dppf<0x141>(v));
    v = fmaxf(v, dppf<0x140>(v));
    v = fmaxf(v, dppf<0x142, 0xa>(v));
    v = fmaxf(v, dppf<0x143, 0xc>(v));
    return __builtin_bit_cast(float, __builtin_amdgcn_readlane(__builtin_bit_cast(int, v), 63));
}
__device__ __forceinline__ float wave_dpp_sum(float v) {
    v += dppf<0xB1>(v);
    v += dppf<0x4E>(v);
    v += dppf<0x141>(v);
    v += dppf<0x140>(v);
    v += dppf<0x142, 0xa>(v);
    v += dppf<0x143, 0xc>(v);
    return __builtin_bit_cast(float, __builtin_amdgcn_readlane(__builtin_bit_cast(int, v), 63));
}

// ---------- P0: per-m codebook sums S_m and Gram G_m = C^T C; zero stats ----------
__global__ void k_gram(const float* __restrict__ Ck, float* __restrict__ G,
                       float* __restrict__ S, double* __restrict__ stats) {
    __shared__ float CT[DD][KK + 4];
    const int m = blockIdx.x, part = blockIdx.y;
    const int t = threadIdx.x, wid = t >> 6, lane = t & 63;
    if (m == 0 && part == 0 && t < 2 * MM) stats[t] = 0.0;
    const float4* cp = (const float4*)(Ck + ((size_t)m * KK + t) * DD);
    #pragma unroll
    for (int i = 0; i < 8; ++i) {
        float4 v = cp[i];
        CT[4*i+0][t] = v.x; CT[4*i+1][t] = v.y;
        CT[4*i+2][t] = v.z; CT[4*i+3][t] = v.w;
    }
    __syncthreads();
    #pragma unroll 1
    for (int ei = 0; ei < 32; ++ei) {
        const int e = part * 128 + wid * 32 + ei;
        const int i = e >> 5, j = e & 31;
        float acc = 0.f;
        #pragma unroll
        for (int c4 = 0; c4 < 4; ++c4)
            acc = fmaf(CT[i][lane + 64*c4], CT[j][lane + 64*c4], acc);
        acc = wave_fsum(acc);
        if (lane == 0) G[((size_t)m * DD + i) * DD + j] = acc;
    }
    if (part == 0 && wid == 0) {
        #pragma unroll 1
        for (int d = 0; d < DD; ++d) {
            float a = 0.f;
            #pragma unroll
            for (int c4 = 0; c4 < 4; ++c4) a += CT[d][lane + 64*c4];
            a = wave_fsum(a);
            if (lane == 0) S[m * DD + d] = a;
        }
    }
}

// ---------- P1: FUSED normalize + stats (one x pass, thread-per-(b,m)) ----------
__global__ void k_ns(const float* __restrict__ x, float* __restrict__ xn,
                     const float* __restrict__ G, const float* __restrict__ S,
                     double* __restrict__ stats) {
    const int m = blockIdx.x;
    const int b = blockIdx.y * 256 + threadIdx.x;
    float xv[DD];
    {
        const float4* xp = (const float4*)(x + (size_t)b * FEAT_DIM + m * DD);
        #pragma unroll
        for (int i = 0; i < 8; ++i) {
            float4 v = xp[i];
            xv[4*i+0]=v.x; xv[4*i+1]=v.y; xv[4*i+2]=v.z; xv[4*i+3]=v.w;
        }
    }
    float ss = 0.f;
    #pragma unroll
    for (int i = 0; i < DD; ++i) ss = fmaf(xv[i], xv[i], ss);
    const float rn = 1.0f / fmaxf(sqrtf(ss), 1e-12f);
    {
        float4* op = (float4*)(xn + (size_t)b * FEAT_DIM + m * DD);
        #pragma unroll
        for (int i = 0; i < 8; ++i) {
            float4 o = {xv[4*i+0]*rn, xv[4*i+1]*rn, xv[4*i+2]*rn, xv[4*i+3]*rn};
            op[i] = o;
        }
    }
    // quadratic form on RAW x, scaled after: sum = rn*(x.S), sumsq = rn^2*(x^T G x)
    const float4* Gp = (const float4*)(G + (size_t)m * DD * DD);   // block-uniform
    const float*  Sp = S + m * DD;
    float q = 0.f, s = 0.f;
    #pragma unroll 4
    for (int i = 0; i < DD; ++i) {
        float y = 0.f;
        #pragma unroll
        for (int jv = 0; jv < 8; ++jv) {
            float4 g = Gp[i * 8 + jv];
            y = fmaf(g.x, xv[4*jv+0], y); y = fmaf(g.y, xv[4*jv+1], y);
            y = fmaf(g.z, xv[4*jv+2], y); y = fmaf(g.w, xv[4*jv+3], y);
        }
        q = fmaf(y, xv[i], q);
    }
    #pragma unroll
    for (int i = 0; i < DD; ++i) s = fmaf(Sp[i], xv[i], s);
    q = q * rn * rn;
    s = s * rn;
    q = wave_fsum(q); s = wave_fsum(s);
    __shared__ float lq[4], ls[4];
    const int wid = threadIdx.x >> 6, lane = threadIdx.x & 63;
    if (lane == 0) { lq[wid] = q; ls[wid] = s; }
    __syncthreads();
    if (threadIdx.x == 0) {
        atomicAdd(&stats[2*m],   (double)((ls[0]+ls[1])+(ls[2]+ls[3])));
        atomicAdd(&stats[2*m+1], (double)((lq[0]+lq[1])+(lq[2]+lq[3])));
    }
}

// ---------- P2: wave-per-(b,m), EXACT R12 hot loop (store-only FINISH) ----------
template <int BT>
__global__ __launch_bounds__(256, 2)
void k_main(const float* __restrict__ xn, const float* __restrict__ Ck,
            const double* __restrict__ stats,
            float* __restrict__ hard, float* __restrict__ soft,
            float* __restrict__ part) {
    const int m = blockIdx.x;
    const int wid = threadIdx.x >> 6, lane = threadIdx.x & 63;

    const double Ninv = 1.0 / ((double)BB * (double)KK);
    const double mu  = stats[2*m] * Ninv;
    const double var = stats[2*m+1] * Ninv - mu * mu;
    const float rstd = (float)(1.0 / sqrt(var + (double)BN_EPS));
    // softmax is scale-invariant: p = exp2(d * rstd*log2e); shift cancels
    const float c1 = rstd * 1.4426950408889634f;

    // lane owns codewords k = 4*lane + j, register-resident across the b-loop
    float c[4][DD];
    #pragma unroll
    for (int j = 0; j < 4; ++j) {
        const float4* cp = (const float4*)(Ck + ((size_t)m * KK + 4*lane + j) * DD);
        #pragma unroll
        for (int i = 0; i < 8; ++i) {
            float4 v = cp[i];
            c[j][4*i+0]=v.x; c[j][4*i+1]=v.y; c[j][4*i+2]=v.z; c[j][4*i+3]=v.w;
        }
    }

    const int b_base = blockIdx.y * (4 * BT) + wid;

    auto loadslice = [&](float4 (&q)[8], int b) {
        const int bu = __builtin_amdgcn_readfirstlane(b);
        const float4* xp = (const float4*)(xn + (size_t)bu * FEAT_DIM + m * DD);
        #pragma unroll
        for (int i = 0; i < 8; ++i) q[i] = xp[i];
    };

    auto process = [&](const float4 (&q)[8], int b) {
        float d0=0.f, d1=0.f, d2=0.f, d3=0.f;
        #pragma unroll
        for (int i = 0; i < 8; ++i) {
            const float4 q4 = q[i];
            d0 = fmaf(q4.x, c[0][4*i+0], d0); d0 = fmaf(q4.y, c[0][4*i+1], d0);
            d0 = fmaf(q4.z, c[0][4*i+2], d0); d0 = fmaf(q4.w, c[0][4*i+3], d0);
            d1 = fmaf(q4.x, c[1][4*i+0], d1); d1 = fmaf(q4.y, c[1][4*i+1], d1);
            d1 = fmaf(q4.z, c[1][4*i+2], d1); d1 = fmaf(q4.w, c[1][4*i+3], d1);
            d2 = fmaf(q4.x, c[2][4*i+0], d2); d2 = fmaf(q4.y, c[2][4*i+1], d2);
            d2 = fmaf(q4.z, c[2][4*i+2], d2); d2 = fmaf(q4.w, c[2][4*i+3], d2);
            d3 = fmaf(q4.x, c[3][4*i+0], d3); d3 = fmaf(q4.y, c[3][4*i+1], d3);
            d3 = fmaf(q4.z, c[3][4*i+2], d3); d3 = fmaf(q4.w, c[3][4*i+3], d3);
        }

        // softmax (unshifted, scale-invariant) — chain independent of argmax chain
        const float p0 = exp2f(d0 * c1);
        const float p1 = exp2f(d1 * c1);
        const float p2 = exp2f(d2 * c1);
        const float p3 = exp2f(d3 * c1);

        // argmax: DPP wave-max (SGPR broadcast), ballot + scalar ffs
        const float mx = wave_dpp_max(fmaxf(fmaxf(d0, d1), fmaxf(d2, d3)));
        const unsigned long long m0 = __ballot(d0 == mx);
        const unsigned long long m1 = __ballot(d1 == mx);
        const unsigned long long m2 = __ballot(d2 == mx);
        const unsigned long long m3 = __ballot(d3 == mx);
        const int k0 = m0 ? 4*__builtin_ctzll(m0)+0 : 0x7fffffff;
        const int k1 = m1 ? 4*__builtin_ctzll(m1)+1 : 0x7fffffff;
        const int k2 = m2 ? 4*__builtin_ctzll(m2)+2 : 0x7fffffff;
        const int k3 = m3 ? 4*__builtin_ctzll(m3)+3 : 0x7fffffff;
        const int bi = min(min(k0, k1), min(k2, k3));   // first-index tie-break

        const float tot = wave_dpp_sum((p0 + p1) + (p2 + p3));
        const float inv = __builtin_amdgcn_rcpf(tot);

        f32x4 o = {p0*inv, p1*inv, p2*inv, p3*inv};
        __builtin_nontemporal_store(o, (f32x4*)(soft + ((size_t)b * MM + m) * KK) + lane);
        if (lane == 0) {
            hard[(size_t)b * MM + m] = (float)bi;
            part[(size_t)m * BB + b] = 2.f - 2.f * mx;  // reg identity: 2-2*maxdot
        }
        // xhat gather lives in k_xhat — keep this loop allocation-clean
    };

    // ping-pong double-buffer, no register copies (R6/R12 structure)
    float4 A[8], Bv[8];
    loadslice(A, b_base);
    #pragma unroll 1
    for (int it = 0; it < BT; it += 2) {
        loadslice(Bv, b_base + 4 * (it + 1));           // BT even: it+1 < BT always
        process(A, b_base + 4 * it);
        if (it + 2 < BT) loadslice(A, b_base + 4 * (it + 2));
        process(Bv, b_base + 4 * (it + 1));
    }
}

// ---------- P3: xhat[b][m] = Ck[m][hard[b][m]] — gather isolated here ----------
__global__ void k_xhat(const float* __restrict__ Ck, const float* __restrict__ hard,
                       float* __restrict__ xhat) {
    const int t = blockIdx.x * 256 + threadIdx.x;   // t < B*M*8
    const int i = t & 7, bm = t >> 3;
    const int m = bm & (MM - 1);
    const int k = (int)hard[bm];
    f32x4 cw = ((const f32x4*)(Ck + ((size_t)m * KK + k) * DD))[i];
    __builtin_nontemporal_store(cw, ((f32x4*)xhat) + (size_t)bm * 8 + i);
}

// ---------- P4: reg[b] = sum_m part[m][b] ----------
__global__ void k_regsum(const float* __restrict__ part, float* __restrict__ reg) {
    const int b = blockIdx.x * 256 + threadIdx.x;
    float a = 0.f;
    #pragma unroll
    for (int mm = 0; mm < MM; ++mm) a += part[(size_t)mm * BB + b];
    reg[b] = a;
}

extern "C" void kernel_launch(void* const* d_in, const int* in_sizes, int n_in,
                              void* d_out, int out_size, void* d_ws, size_t ws_size,
                              hipStream_t stream) {
    const float* x  = (const float*)d_in[0];
    const float* Ck = (const float*)d_in[1];

    float* out   = (float*)d_out;
    float* xhat  = out;                                   // B*FEAT
    float* hard  = xhat  + (size_t)BB * FEAT_DIM;         // B*M
    float* soft  = hard  + (size_t)BB * MM;               // B*M*K
    float* xnorm = soft  + (size_t)BB * MM * KK;          // B*FEAT
    float* reg   = xnorm + (size_t)BB * FEAT_DIM;         // B

    double* stats = (double*)d_ws;                        // M*2 doubles
    float* partb  = (float*)d_ws + 256;                   // M*B floats (1 MB) scratch
    float* Gbuf = soft;                                   // M*D*D floats (scratch, pre-k_main)
    float* Sbuf = soft + (size_t)MM * DD * DD;            // M*D floats

    k_gram<<<dim3(MM, 8), 256, 0, stream>>>(Ck, Gbuf, Sbuf, stats);
    k_ns<<<dim3(MM, BB / 256), 256, 0, stream>>>(x, xnorm, Gbuf, Sbuf, stats);
    constexpr int BT = 32;
    k_main<BT><<<dim3(MM, BB / (4 * BT)), 256, 0, stream>>>(xnorm, Ck, stats, hard, soft, partb);
    k_xhat<<<(BB * MM * 8) / 256, 256, 0, stream>>>(Ck, hard, xhat);
    k_regsum<<<BB / 256, 256, 0, stream>>>(partb, reg);
}

// Round 16
// 157.616 us; speedup vs baseline: 1.4097x; 1.0085x over previous
//
#include <hip/hip_runtime.h>
#include <cmath>

#define FEAT_DIM 1024
#define MM 32
#define KK 256
#define DD 32
#define BB 8192

constexpr float BN_EPS = 1e-5f;

typedef float f32x4 __attribute__((ext_vector_type(4)));

__device__ __forceinline__ float wave_fsum(float v) {
    #pragma unroll
    for (int s = 32; s >= 1; s >>= 1) v += __shfl_xor(v, s);
    return v;
}

// ---- DPP-based full-wave reductions: VALU-rate, result broadcast via SGPR ----
template <int CTRL, int RM = 0xf>
__device__ __forceinline__ float dppf(float v) {
    int r = __builtin_amdgcn_update_dpp(__builtin_bit_cast(int, v),
                                        __builtin_bit_cast(int, v),
                                        CTRL, RM, 0xf, false);
    return __builtin_bit_cast(float, r);
}
__device__ __forceinline__ float wave_dpp_max(float v) {
    v = fmaxf(v, dppf<0xB1>(v));
    v = fmaxf(v, dppf<0x4E>(v));
    v = fmaxf(v, dppf<0x141>(v));
    v = fmaxf(v, dppf<0x140>(v));
    v = fmaxf(v, dppf<0x142, 0xa>(v));
    v = fmaxf(v, dppf<0x143, 0xc>(v));
    return __builtin_bit_cast(float, __builtin_amdgcn_readlane(__builtin_bit_cast(int, v), 63));
}
__device__ __forceinline__ float wave_dpp_sum(float v) {
    v += dppf<0xB1>(v);
    v += dppf<0x4E>(v);
    v += dppf<0x141>(v);
    v += dppf<0x140>(v);
    v += dppf<0x142, 0xa>(v);
    v += dppf<0x143, 0xc>(v);
    return __builtin_bit_cast(float, __builtin_amdgcn_readlane(__builtin_bit_cast(int, v), 63));
}

// ---------- P0: per-m codebook sums S_m and Gram G_m = C^T C; zero stats ----------
__global__ void k_gram(const float* __restrict__ Ck, float* __restrict__ G,
                       float* __restrict__ S, double* __restrict__ stats) {
    __shared__ float CT[DD][KK + 4];
    const int m = blockIdx.x, part = blockIdx.y;
    const int t = threadIdx.x, wid = t >> 6, lane = t & 63;
    if (m == 0 && part == 0 && t < 2 * MM) stats[t] = 0.0;
    const float4* cp = (const float4*)(Ck + ((size_t)m * KK + t) * DD);
    #pragma unroll
    for (int i = 0; i < 8; ++i) {
        float4 v = cp[i];
        CT[4*i+0][t] = v.x; CT[4*i+1][t] = v.y;
        CT[4*i+2][t] = v.z; CT[4*i+3][t] = v.w;
    }
    __syncthreads();
    #pragma unroll 1
    for (int ei = 0; ei < 32; ++ei) {
        const int e = part * 128 + wid * 32 + ei;
        const int i = e >> 5, j = e & 31;
        float acc = 0.f;
        #pragma unroll
        for (int c4 = 0; c4 < 4; ++c4)
            acc = fmaf(CT[i][lane + 64*c4], CT[j][lane + 64*c4], acc);
        acc = wave_fsum(acc);
        if (lane == 0) G[((size_t)m * DD + i) * DD + j] = acc;
    }
    if (part == 0 && wid == 0) {
        #pragma unroll 1
        for (int d = 0; d < DD; ++d) {
            float a = 0.f;
            #pragma unroll
            for (int c4 = 0; c4 < 4; ++c4) a += CT[d][lane + 64*c4];
            a = wave_fsum(a);
            if (lane == 0) S[m * DD + d] = a;
        }
    }
}

// ---------- P1: FUSED normalize + stats (one x pass, thread-per-(b,m)) ----------
__global__ void k_ns(const float* __restrict__ x, float* __restrict__ xn,
                     const float* __restrict__ G, const float* __restrict__ S,
                     double* __restrict__ stats) {
    const int m = blockIdx.x;
    const int b = blockIdx.y * 256 + threadIdx.x;
    float xv[DD];
    {
        const float4* xp = (const float4*)(x + (size_t)b * FEAT_DIM + m * DD);
        #pragma unroll
        for (int i = 0; i < 8; ++i) {
            float4 v = xp[i];
            xv[4*i+0]=v.x; xv[4*i+1]=v.y; xv[4*i+2]=v.z; xv[4*i+3]=v.w;
        }
    }
    float ss = 0.f;
    #pragma unroll
    for (int i = 0; i < DD; ++i) ss = fmaf(xv[i], xv[i], ss);
    const float rn = 1.0f / fmaxf(sqrtf(ss), 1e-12f);
    {
        float4* op = (float4*)(xn + (size_t)b * FEAT_DIM + m * DD);
        #pragma unroll
        for (int i = 0; i < 8; ++i) {
            float4 o = {xv[4*i+0]*rn, xv[4*i+1]*rn, xv[4*i+2]*rn, xv[4*i+3]*rn};
            op[i] = o;
        }
    }
    // quadratic form on RAW x, scaled after: sum = rn*(x.S), sumsq = rn^2*(x^T G x)
    const float4* Gp = (const float4*)(G + (size_t)m * DD * DD);   // block-uniform
    const float*  Sp = S + m * DD;
    float q = 0.f, s = 0.f;
    #pragma unroll 4
    for (int i = 0; i < DD; ++i) {
        float y = 0.f;
        #pragma unroll
        for (int jv = 0; jv < 8; ++jv) {
            float4 g = Gp[i * 8 + jv];
            y = fmaf(g.x, xv[4*jv+0], y); y = fmaf(g.y, xv[4*jv+1], y);
            y = fmaf(g.z, xv[4*jv+2], y); y = fmaf(g.w, xv[4*jv+3], y);
        }
        q = fmaf(y, xv[i], q);
    }
    #pragma unroll
    for (int i = 0; i < DD; ++i) s = fmaf(Sp[i], xv[i], s);
    q = q * rn * rn;
    s = s * rn;
    q = wave_fsum(q); s = wave_fsum(s);
    __shared__ float lq[4], ls[4];
    const int wid = threadIdx.x >> 6, lane = threadIdx.x & 63;
    if (lane == 0) { lq[wid] = q; ls[wid] = s; }
    __syncthreads();
    if (threadIdx.x == 0) {
        atomicAdd(&stats[2*m],   (double)((ls[0]+ls[1])+(ls[2]+ls[3])));
        atomicAdd(&stats[2*m+1], (double)((lq[0]+lq[1])+(lq[2]+lq[3])));
    }
}

// ---------- P2: wave-per-(b,m), EXACT R12 hot loop (store-only FINISH), BT=64 ----------
template <int BT>
__global__ __launch_bounds__(256, 2)
void k_main(const float* __restrict__ xn, const float* __restrict__ Ck,
            const double* __restrict__ stats,
            float* __restrict__ hard, float* __restrict__ soft,
            float* __restrict__ part) {
    const int m = blockIdx.x;
    const int wid = threadIdx.x >> 6, lane = threadIdx.x & 63;

    const double Ninv = 1.0 / ((double)BB * (double)KK);
    const double mu  = stats[2*m] * Ninv;
    const double var = stats[2*m+1] * Ninv - mu * mu;
    const float rstd = (float)(1.0 / sqrt(var + (double)BN_EPS));
    // softmax is scale-invariant: p = exp2(d * rstd*log2e); shift cancels
    const float c1 = rstd * 1.4426950408889634f;

    // lane owns codewords k = 4*lane + j, register-resident across the b-loop
    float c[4][DD];
    #pragma unroll
    for (int j = 0; j < 4; ++j) {
        const float4* cp = (const float4*)(Ck + ((size_t)m * KK + 4*lane + j) * DD);
        #pragma unroll
        for (int i = 0; i < 8; ++i) {
            float4 v = cp[i];
            c[j][4*i+0]=v.x; c[j][4*i+1]=v.y; c[j][4*i+2]=v.z; c[j][4*i+3]=v.w;
        }
    }

    const int b_base = blockIdx.y * (4 * BT) + wid;

    auto loadslice = [&](float4 (&q)[8], int b) {
        const int bu = __builtin_amdgcn_readfirstlane(b);
        const float4* xp = (const float4*)(xn + (size_t)bu * FEAT_DIM + m * DD);
        #pragma unroll
        for (int i = 0; i < 8; ++i) q[i] = xp[i];
    };

    auto process = [&](const float4 (&q)[8], int b) {
        float d0=0.f, d1=0.f, d2=0.f, d3=0.f;
        #pragma unroll
        for (int i = 0; i < 8; ++i) {
            const float4 q4 = q[i];
            d0 = fmaf(q4.x, c[0][4*i+0], d0); d0 = fmaf(q4.y, c[0][4*i+1], d0);
            d0 = fmaf(q4.z, c[0][4*i+2], d0); d0 = fmaf(q4.w, c[0][4*i+3], d0);
            d1 = fmaf(q4.x, c[1][4*i+0], d1); d1 = fmaf(q4.y, c[1][4*i+1], d1);
            d1 = fmaf(q4.z, c[1][4*i+2], d1); d1 = fmaf(q4.w, c[1][4*i+3], d1);
            d2 = fmaf(q4.x, c[2][4*i+0], d2); d2 = fmaf(q4.y, c[2][4*i+1], d2);
            d2 = fmaf(q4.z, c[2][4*i+2], d2); d2 = fmaf(q4.w, c[2][4*i+3], d2);
            d3 = fmaf(q4.x, c[3][4*i+0], d3); d3 = fmaf(q4.y, c[3][4*i+1], d3);
            d3 = fmaf(q4.z, c[3][4*i+2], d3); d3 = fmaf(q4.w, c[3][4*i+3], d3);
        }

        // softmax (unshifted, scale-invariant) — chain independent of argmax chain
        const float p0 = exp2f(d0 * c1);
        const float p1 = exp2f(d1 * c1);
        const float p2 = exp2f(d2 * c1);
        const float p3 = exp2f(d3 * c1);

        // argmax: DPP wave-max (SGPR broadcast), ballot + scalar ffs
        const float mx = wave_dpp_max(fmaxf(fmaxf(d0, d1), fmaxf(d2, d3)));
        const unsigned long long m0 = __ballot(d0 == mx);
        const unsigned long long m1 = __ballot(d1 == mx);
        const unsigned long long m2 = __ballot(d2 == mx);
        const unsigned long long m3 = __ballot(d3 == mx);
        const int k0 = m0 ? 4*__builtin_ctzll(m0)+0 : 0x7fffffff;
        const int k1 = m1 ? 4*__builtin_ctzll(m1)+1 : 0x7fffffff;
        const int k2 = m2 ? 4*__builtin_ctzll(m2)+2 : 0x7fffffff;
        const int k3 = m3 ? 4*__builtin_ctzll(m3)+3 : 0x7fffffff;
        const int bi = min(min(k0, k1), min(k2, k3));   // first-index tie-break

        const float tot = wave_dpp_sum((p0 + p1) + (p2 + p3));
        const float inv = __builtin_amdgcn_rcpf(tot);

        f32x4 o = {p0*inv, p1*inv, p2*inv, p3*inv};
        __builtin_nontemporal_store(o, (f32x4*)(soft + ((size_t)b * MM + m) * KK) + lane);
        if (lane == 0) {
            hard[(size_t)b * MM + m] = (float)bi;
            part[(size_t)m * BB + b] = 2.f - 2.f * mx;  // reg identity: 2-2*maxdot
        }
        // xhat gather lives in k_post — keep this loop allocation-clean
    };

    // ping-pong double-buffer, no register copies (R6/R12 structure)
    float4 A[8], Bv[8];
    loadslice(A, b_base);
    #pragma unroll 1
    for (int it = 0; it < BT; it += 2) {
        loadslice(Bv, b_base + 4 * (it + 1));           // BT even: it+1 < BT always
        process(A, b_base + 4 * it);
        if (it + 2 < BT) loadslice(A, b_base + 4 * (it + 2));
        process(Bv, b_base + 4 * (it + 1));
    }
}

// ---------- P3: fused epilogue — xhat gather + reg reduction (disjoint block ranges) ----
#define XHAT_BLOCKS ((BB * MM * 8) / 256)
__global__ void k_post(const float* __restrict__ Ck, const float* __restrict__ hard,
                       float* __restrict__ xhat, const float* __restrict__ part,
                       float* __restrict__ reg) {
    if (blockIdx.x < XHAT_BLOCKS) {
        const int t = blockIdx.x * 256 + threadIdx.x;   // t < B*M*8
        const int i = t & 7, bm = t >> 3;
        const int m = bm & (MM - 1);
        const int k = (int)hard[bm];
        f32x4 cw = ((const f32x4*)(Ck + ((size_t)m * KK + k) * DD))[i];
        __builtin_nontemporal_store(cw, ((f32x4*)xhat) + (size_t)bm * 8 + i);
    } else {
        const int b = (blockIdx.x - XHAT_BLOCKS) * 256 + threadIdx.x;
        float a = 0.f;
        #pragma unroll
        for (int mm = 0; mm < MM; ++mm) a += part[(size_t)mm * BB + b];
        reg[b] = a;
    }
}

extern "C" void kernel_launch(void* const* d_in, const int* in_sizes, int n_in,
                              void* d_out, int out_size, void* d_ws, size_t ws_size,
                              hipStream_t stream) {
    const float* x  = (const float*)d_in[0];
    const float* Ck = (const float*)d_in[1];

    float* out   = (float*)d_out;
    float* xhat  = out;                                   // B*FEAT
    float* hard  = xhat  + (size_t)BB * FEAT_DIM;         // B*M
    float* soft  = hard  + (size_t)BB * MM;               // B*M*K
    float* xnorm = soft  + (size_t)BB * MM * KK;          // B*FEAT
    float* reg   = xnorm + (size_t)BB * FEAT_DIM;         // B

    double* stats = (double*)d_ws;                        // M*2 doubles
    float* partb  = (float*)d_ws + 256;                   // M*B floats (1 MB) scratch
    float* Gbuf = soft;                                   // M*D*D floats (scratch, pre-k_main)
    float* Sbuf = soft + (size_t)MM * DD * DD;            // M*D floats

    k_gram<<<dim3(MM, 8), 256, 0, stream>>>(Ck, Gbuf, Sbuf, stats);
    k_ns<<<dim3(MM, BB / 256), 256, 0, stream>>>(x, xnorm, Gbuf, Sbuf, stats);
    constexpr int BT = 64;
    k_main<BT><<<dim3(MM, BB / (4 * BT)), 256, 0, stream>>>(xnorm, Ck, stats, hard, soft, partb);
    k_post<<<XHAT_BLOCKS + BB / 256, 256, 0, stream>>>(Ck, hard, xhat, partb, reg);
}